// Round 7
// baseline (1305.223 us; speedup 1.0000x reference)
//
#include <hip/hip_runtime.h>
#include <hip/hip_fp16.h>

#define T_SEQ   2048
#define HID     50
#define NGATES  200
#define NPAD    256     // 16 N-tiles of 16 -> uniform 4 tiles/wave, branch-free
#define KPAD    64      // 50 h + 13 onehot + 1 bias = 64 exactly (f16 single-precision)
#define MB      4       // batch rows per block
#define NBLK    512     // 2048 / MB  -> 2 blocks/CU
#define NTHR    256     // 4 waves
#define HSTR    72      // hA row stride in ushorts (144B: 16B-aligned, bank-staggered)

typedef __attribute__((ext_vector_type(8))) _Float16 half8;
typedef __attribute__((ext_vector_type(4))) float    f32x4;

__device__ __forceinline__ ushort f16b(float f) {
    return __half_as_ushort(__float2half(f));   // RNE
}
__device__ __forceinline__ float sigm(float x) {
    return 1.f / (1.f + __expf(-x));
}
__device__ __forceinline__ float tanh_(float x) {
    float xc = fminf(fmaxf(x, -15.f), 15.f);
    float e = __expf(2.f * xc);
    return (e - 1.f) / (e + 1.f);
}

// B matrix [NPAD][KPAD] f16 bits, K-augmented, single precision:
//  k in [0,50)  : W_hh[n][k]      (x h)
//  k in [50,63) : Ttab[v=k-50][n] (x onehot)   Ttab[v][n]=sum_e embed[v,e]*W_ih[n,e]
//  k == 63      : b_ih[n]+b_hh[n] (x 1)
//  n >= 200     : zero (pad tiles)
__global__ void build_B(const float* __restrict__ embed,
                        const float* __restrict__ Wih,
                        const float* __restrict__ Whh,
                        const float* __restrict__ bih,
                        const float* __restrict__ bhh,
                        ushort* __restrict__ B) {
    int idx = blockIdx.x * blockDim.x + threadIdx.x;
    if (idx >= NPAD * KPAD) return;
    int n = idx >> 6;
    int k = idx & 63;
    ushort v = 0;
    if (n < NGATES) {
        if (k < 50) {
            v = f16b(Whh[n * HID + k]);
        } else if (k < 63) {
            int vv = k - 50;
            float t = 0.f;
            for (int e = 0; e < HID; ++e)
                t = fmaf(embed[vv * HID + e], Wih[n * HID + e], t);
            v = f16b(t);
        } else {
            v = f16b(bih[n] + bhh[n]);
        }
    }
    B[idx] = v;
}

// 512 blocks x 256 threads (4 waves); block handles batch rows [blockIdx.x*4, +4).
// B fragments pinned in AGPRs ("a" class): MFMA reads AGPR operands directly
// on gfx950 -> no per-step accvgpr_read flood, no VGPR pressure.
__global__ __launch_bounds__(256, 2) void lstm_mfma(
    const int*    __restrict__ x,
    const ushort* __restrict__ Bmat,
    const float*  __restrict__ W1,
    const float*  __restrict__ b1,
    const float*  __restrict__ W2,
    const float*  __restrict__ b2,
    float*        __restrict__ out)
{
    const int t   = threadIdx.x;
    const int w   = t >> 6;
    const int l   = t & 63;
    const int c16 = l & 15;     // MFMA: A row m / B,C col n
    const int q   = l >> 4;     // MFMA: k-group / C row-group
    const int m   = t & 3;      // act: batch row
    const int u   = t >> 2;     // act: hidden unit (valid if t<200)
    const bool actv = (t < 200);

    __shared__ __align__(16) ushort hA[MB * HSTR];
    __shared__ __align__(16) float  G[NPAD * MB];   // [n][m], stride 4

    // wave w owns tiles 4w..4w+3; 2 k-frags each = 8 half8.
    half8 bf[4][2];
    {
        const ushort* bp = Bmat + (w * 4 * 16 + c16) * KPAD + q * 8;
        #pragma unroll
        for (int j = 0; j < 4; ++j)
            #pragma unroll
            for (int kf = 0; kf < 2; ++kf)
                bf[j][kf] = *(const half8*)(bp + j * 16 * KPAD + kf * 32);
    }
    // Pin into AGPR class: one-time accvgpr_write in the preamble; MFMA then
    // consumes the AGPRs in place every iteration.
    #pragma unroll
    for (int j = 0; j < 4; ++j)
        #pragma unroll
        for (int kf = 0; kf < 2; ++kf)
            asm volatile("" : "+a"(bf[j][kf]));

    for (int i = t; i < MB * HSTR; i += NTHR) hA[i] = 0;

    const long xbase = (long)blockIdx.x * MB * T_SEQ;
    int tok_cur = 0, tok_nxt = 0;
    if (t < MB) {
        tok_cur = x[xbase + (long)m * T_SEQ + 0];
        tok_nxt = x[xbase + (long)m * T_SEQ + 1];
    }
    __syncthreads();
    if (t < MB) {
        hA[m * HSTR + 63] = 0x3C00;             // bias slot = 1.0 (f16)
        hA[m * HSTR + 50 + tok_cur] = 0x3C00;   // onehot
    }
    float c = 0.f;

    // A rows 4..15 wrap onto rows 0..3 (duplicates); only q==0 C rows stored.
    const ushort* hrow = hA + (c16 & 3) * HSTR;
    const bool mfma_full = (w < 3);   // wave 3's tiles 13..15 are zero pad

    for (int step = 0; step < T_SEQ; ++step) {
        __syncthreads();  // hA ready

        half8 a[2];
        #pragma unroll
        for (int kf = 0; kf < 2; ++kf)
            a[kf] = *(const half8*)(hrow + kf * 32 + q * 8);

        // tile j=0 always (wave 3's tile 12 holds n=192..199 real)
        {
            f32x4 z = {0.f, 0.f, 0.f, 0.f};
            z = __builtin_amdgcn_mfma_f32_16x16x32_f16(a[0], bf[0][0], z, 0, 0, 0);
            z = __builtin_amdgcn_mfma_f32_16x16x32_f16(a[1], bf[0][1], z, 0, 0, 0);
            if (q == 0) {
                int n = (w * 4 + 0) * 16 + c16;
                *(f32x4*)(G + n * MB) = z;
            }
        }
        if (mfma_full) {   // wave-uniform branch (s_cbranch, no divergence)
            #pragma unroll
            for (int j = 1; j < 4; ++j) {
                f32x4 z = {0.f, 0.f, 0.f, 0.f};
                z = __builtin_amdgcn_mfma_f32_16x16x32_f16(a[0], bf[j][0], z, 0, 0, 0);
                z = __builtin_amdgcn_mfma_f32_16x16x32_f16(a[1], bf[j][1], z, 0, 0, 0);
                if (q == 0) {
                    int n = (w * 4 + j) * 16 + c16;
                    *(f32x4*)(G + n * MB) = z;
                }
            }
        }
        __syncthreads();  // G ready

        if (actv) {
            float gi = G[u * MB + m];                 // addr = t (contiguous)
            float gf = G[(50 + u) * MB + m];
            float gg = G[(100 + u) * MB + m];
            float go = G[(150 + u) * MB + m];
            float iv = sigm(gi);
            float fv = sigm(gf);
            float gv = tanh_(gg);
            float ov = sigm(go);
            c = fv * c + iv * gv;
            float h = ov * tanh_(c);
            hA[m * HSTR + u] = f16b(h);               // single f16 h
        }
        if (t < MB) {
            int pf = 0;
            if (step + 2 < T_SEQ) pf = x[xbase + (long)m * T_SEQ + step + 2];
            hA[m * HSTR + 50 + tok_cur] = 0;
            if (step + 1 < T_SEQ)
                hA[m * HSTR + 50 + tok_nxt] = 0x3C00;
            tok_cur = tok_nxt;
            tok_nxt = pf;
        }
    }

    // Epilogue MLP
    __syncthreads();
    if (actv) {   // u < 50
        float a = b1[u];
        const float* wr = W1 + u * HID;
        #pragma unroll 10
        for (int k = 0; k < HID; ++k) {
            float hk = __half2float(__ushort_as_half(hA[m * HSTR + k]));
            a = fmaf(wr[k], hk, a);
        }
        G[u * MB + m] = fmaxf(a, 0.f);
    }
    __syncthreads();
    if (t < MB) {
        float a = b2[0];
        #pragma unroll 10
        for (int j = 0; j < HID; ++j)
            a = fmaf(W2[j], G[j * MB + m], a);
        out[blockIdx.x * MB + m] = a;
    }
}

extern "C" void kernel_launch(void* const* d_in, const int* in_sizes, int n_in,
                              void* d_out, int out_size, void* d_ws, size_t ws_size,
                              hipStream_t stream) {
    const int*   x     = (const int*)  d_in[0];
    const float* embed = (const float*)d_in[1];
    const float* W_ih  = (const float*)d_in[2];
    const float* W_hh  = (const float*)d_in[3];
    const float* b_ih  = (const float*)d_in[4];
    const float* b_hh  = (const float*)d_in[5];
    const float* W1    = (const float*)d_in[6];
    const float* b1    = (const float*)d_in[7];
    const float* W2    = (const float*)d_in[8];
    const float* b2    = (const float*)d_in[9];
    float* out = (float*)d_out;

    ushort* Bmat = (ushort*)d_ws;  // NPAD*KPAD*2 = 32,768 B scratch

    build_B<<<(NPAD * KPAD + 255) / 256, 256, 0, stream>>>(
        embed, W_ih, W_hh, b_ih, b_hh, Bmat);

    lstm_mfma<<<NBLK, NTHR, 0, stream>>>(
        x, Bmat, W1, b1, W2, b2, out);
}

// Round 8
// 1139.101 us; speedup vs baseline: 1.1458x; 1.1458x over previous
//
#include <hip/hip_runtime.h>
#include <hip/hip_fp16.h>

#define T_SEQ   2048
#define HID     50
#define NGATES  200
#define NPAD    256     // 16 N-tiles of 16 -> uniform 4 tiles/wave, branch-free
#define KPAD    64      // 50 h + 13 onehot + 1 bias = 64 exactly (f16)
#define MB      2       // batch rows per block
#define NBLK    1024    // 2048 / MB  -> 4 blocks/CU
#define NTHR    256     // 4 waves
#define HSTR    72      // hA row stride in ushorts (144B)

typedef __attribute__((ext_vector_type(8))) _Float16 half8;
typedef __attribute__((ext_vector_type(4))) float    f32x4;
typedef __attribute__((ext_vector_type(2))) float    f32x2;

__device__ __forceinline__ ushort f16b(float f) {
    return __half_as_ushort(__float2half(f));   // RNE
}
// 1-instruction reciprocal (v_rcp_f32): ~1e-7 rel err, fine vs 3.3e-3 tol.
__device__ __forceinline__ float rcp_(float x) {
    return __builtin_amdgcn_rcpf(x);
}
__device__ __forceinline__ float sigm(float x) {
    return rcp_(1.f + __expf(-x));
}
__device__ __forceinline__ float tanh_(float x) {
    // tanh(x) = 2*sigmoid(2x) - 1; exp handles +-inf cleanly, no clamp needed
    return fmaf(2.f, rcp_(1.f + __expf(-2.f * x)), -1.f);
}

// B matrix [NPAD][KPAD] f16 bits, K-augmented, single precision:
//  k in [0,50)  : W_hh[n][k]      (x h)
//  k in [50,63) : Ttab[v=k-50][n] (x onehot)   Ttab[v][n]=sum_e embed[v,e]*W_ih[n,e]
//  k == 63      : b_ih[n]+b_hh[n] (x 1)
//  n >= 200     : zero (pad tiles)
__global__ void build_B(const float* __restrict__ embed,
                        const float* __restrict__ Wih,
                        const float* __restrict__ Whh,
                        const float* __restrict__ bih,
                        const float* __restrict__ bhh,
                        ushort* __restrict__ B) {
    int idx = blockIdx.x * blockDim.x + threadIdx.x;
    if (idx >= NPAD * KPAD) return;
    int n = idx >> 6;
    int k = idx & 63;
    ushort v = 0;
    if (n < NGATES) {
        if (k < 50) {
            v = f16b(Whh[n * HID + k]);
        } else if (k < 63) {
            int vv = k - 50;
            float t = 0.f;
            for (int e = 0; e < HID; ++e)
                t = fmaf(embed[vv * HID + e], Wih[n * HID + e], t);
            v = f16b(t);
        } else {
            v = f16b(bih[n] + bhh[n]);
        }
    }
    B[idx] = v;
}

// 1024 blocks x 256 threads (4 waves); block handles batch rows [blockIdx.x*2, +2).
// 4 blocks/CU for latency hiding; rcp-based activations (no f32 div sequences).
__global__ __launch_bounds__(256, 4) void lstm_mfma(
    const int*    __restrict__ x,
    const ushort* __restrict__ Bmat,
    const float*  __restrict__ W1,
    const float*  __restrict__ b1,
    const float*  __restrict__ W2,
    const float*  __restrict__ b2,
    float*        __restrict__ out)
{
    const int t   = threadIdx.x;
    const int w   = t >> 6;
    const int l   = t & 63;
    const int c16 = l & 15;     // MFMA: A row m / B,C col n
    const int q   = l >> 4;     // MFMA: k-group / C row-group
    const int m   = t & 1;      // act: batch row
    const int u   = t >> 1;     // act: hidden unit (valid if t<100)
    const bool actv = (t < 2 * HID);   // waves 2,3 skip entirely (execz)

    __shared__ __align__(16) ushort hA[MB * HSTR];
    __shared__ __align__(16) float  G[NPAD * MB];   // [n][m], stride 2

    // wave w owns tiles 4w..4w+3; 2 k-frags each = 8 half8 = 32 VGPRs.
    half8 bf[4][2];
    {
        const ushort* bp = Bmat + (w * 4 * 16 + c16) * KPAD + q * 8;
        #pragma unroll
        for (int j = 0; j < 4; ++j)
            #pragma unroll
            for (int kf = 0; kf < 2; ++kf)
                bf[j][kf] = *(const half8*)(bp + j * 16 * KPAD + kf * 32);
    }
    #pragma unroll
    for (int j = 0; j < 4; ++j)
        #pragma unroll
        for (int kf = 0; kf < 2; ++kf)
            asm volatile("" : "+v"(bf[j][kf]));   // keep producers hoisted

    for (int i = t; i < MB * HSTR; i += NTHR) hA[i] = 0;

    const long xbase = (long)blockIdx.x * MB * T_SEQ;
    int tok_cur = 0, tok_nxt = 0;
    if (t < MB) {
        tok_cur = x[xbase + (long)m * T_SEQ + 0];
        tok_nxt = x[xbase + (long)m * T_SEQ + 1];
    }
    __syncthreads();
    if (t < MB) {
        hA[m * HSTR + 63] = 0x3C00;             // bias slot = 1.0 (f16)
        hA[m * HSTR + 50 + tok_cur] = 0x3C00;   // onehot
    }
    float c = 0.f;

    // A rows 2..15 wrap onto rows 0..1 (duplicates); only q==0 C rows stored.
    const ushort* hrow = hA + (c16 & 1) * HSTR;

    for (int step = 0; step < T_SEQ; ++step) {
        __syncthreads();  // hA ready

        half8 a[2];
        #pragma unroll
        for (int kf = 0; kf < 2; ++kf)
            a[kf] = *(const half8*)(hrow + kf * 32 + q * 8);

        #pragma unroll
        for (int j = 0; j < 4; ++j) {
            f32x4 z = {0.f, 0.f, 0.f, 0.f};
            z = __builtin_amdgcn_mfma_f32_16x16x32_f16(a[0], bf[j][0], z, 0, 0, 0);
            z = __builtin_amdgcn_mfma_f32_16x16x32_f16(a[1], bf[j][1], z, 0, 0, 0);
            if (q == 0) {   // rows 0..1 real (MB=2)
                int n = (w * 4 + j) * 16 + c16;
                f32x2 z2 = {z[0], z[1]};
                *(f32x2*)(G + n * MB) = z2;
            }
        }
        __syncthreads();  // G ready

        if (actv) {
            float gi = G[u * MB + m];                 // addr = t (contiguous)
            float gf = G[(50 + u) * MB + m];
            float gg = G[(100 + u) * MB + m];
            float go = G[(150 + u) * MB + m];
            float iv = sigm(gi);
            float fv = sigm(gf);
            float gv = tanh_(gg);
            float ov = sigm(go);
            c = fv * c + iv * gv;
            float h = ov * tanh_(c);
            hA[m * HSTR + u] = f16b(h);               // single f16 h
        }
        if (t < MB) {
            int pf = 0;
            if (step + 2 < T_SEQ) pf = x[xbase + (long)m * T_SEQ + step + 2];
            hA[m * HSTR + 50 + tok_cur] = 0;
            if (step + 1 < T_SEQ)
                hA[m * HSTR + 50 + tok_nxt] = 0x3C00;
            tok_cur = tok_nxt;
            tok_nxt = pf;
        }
    }

    // Epilogue MLP
    __syncthreads();
    if (actv) {   // u < 50
        float a = b1[u];
        const float* wr = W1 + u * HID;
        #pragma unroll 10
        for (int k = 0; k < HID; ++k) {
            float hk = __half2float(__ushort_as_half(hA[m * HSTR + k]));
            a = fmaf(wr[k], hk, a);
        }
        G[u * MB + m] = fmaxf(a, 0.f);
    }
    __syncthreads();
    if (t < MB) {
        float a = b2[0];
        #pragma unroll 10
        for (int j = 0; j < HID; ++j)
            a = fmaf(W2[j], G[j * MB + m], a);
        out[blockIdx.x * MB + m] = a;
    }
}

extern "C" void kernel_launch(void* const* d_in, const int* in_sizes, int n_in,
                              void* d_out, int out_size, void* d_ws, size_t ws_size,
                              hipStream_t stream) {
    const int*   x     = (const int*)  d_in[0];
    const float* embed = (const float*)d_in[1];
    const float* W_ih  = (const float*)d_in[2];
    const float* W_hh  = (const float*)d_in[3];
    const float* b_ih  = (const float*)d_in[4];
    const float* b_hh  = (const float*)d_in[5];
    const float* W1    = (const float*)d_in[6];
    const float* b1    = (const float*)d_in[7];
    const float* W2    = (const float*)d_in[8];
    const float* b2    = (const float*)d_in[9];
    float* out = (float*)d_out;

    ushort* Bmat = (ushort*)d_ws;  // NPAD*KPAD*2 = 32,768 B scratch

    build_B<<<(NPAD * KPAD + 255) / 256, 256, 0, stream>>>(
        embed, W_ih, W_hh, b_ih, b_hh, Bmat);

    lstm_mfma<<<NBLK, NTHR, 0, stream>>>(
        x, Bmat, W1, b1, W2, b2, out);
}